// Round 1
// baseline (566.849 us; speedup 1.0000x reference)
//
#include <hip/hip_runtime.h>
#include <cstddef>

// Complex MHA: B=8, S=1024, D=512, H=8, DH=64.
// Pipeline (all bf16 MFMA 16x16x32, fp32 accum):
//  1) prep_weights: build 4 interleaved-complex weight matrices Wt[p][n][k] (bf16,
//     transposed so GEMM B-fragments are row-contiguous).
//  2) proj_gemm mode=0 (z=0,1,2): Q/K/V complex linears as real GEMM [8192,1024]@[1024,1024].
//     Epilogue scatters per-head layouts: Qint (r/i interleaved, pre-scaled 1/8),
//     Kc (kr,-ki interleaved -> s_r operand; s_i operand derived in-register),
//     Vtr/Vti (transposed planes for PV B-fragments).
//  3) attn_kernel: flash attention per (b,h,64-row q tile); two online softmaxes
//     (real & imag scores), 4 PV accumulators, P via LDS C->A layout round trip.
//  4) proj_gemm mode=3: output complex linear, writes fp32 d_out.

typedef __attribute__((ext_vector_type(8))) short bf16x8;
typedef __attribute__((ext_vector_type(4))) float f32x4;

__device__ __forceinline__ unsigned short f2bf(float f) {
  union { float f; unsigned u; } v; v.f = f;
  unsigned r = v.u + 0x7FFFu + ((v.u >> 16) & 1u);
  return (unsigned short)(r >> 16);
}
__device__ __forceinline__ unsigned pk2(float a, float b) {
  return (unsigned)f2bf(a) | ((unsigned)f2bf(b) << 16);
}

// ---------------------------------------------------------------- weight prep
__global__ __launch_bounds__(256) void prep_weights(
    const float* __restrict__ wq_r, const float* __restrict__ wq_i,
    const float* __restrict__ wk_r, const float* __restrict__ wk_i,
    const float* __restrict__ wv_r, const float* __restrict__ wv_i,
    const float* __restrict__ wo_r, const float* __restrict__ wo_i,
    unsigned* __restrict__ wt) {  // uint view of bf16 pairs
  int idx = blockIdx.x * 256 + threadIdx.x;  // 4 * 1024 * 512 threads
  int d = idx & 511;
  int n = (idx >> 9) & 1023;
  int p = idx >> 19;
  const float* wr; const float* wi;
  if      (p == 0) { wr = wq_r; wi = wq_i; }
  else if (p == 1) { wr = wk_r; wi = wk_i; }
  else if (p == 2) { wr = wv_r; wi = wv_i; }
  else             { wr = wo_r; wi = wo_i; }
  int j = n >> 1;
  float r = wr[j * 512 + d], im = wi[j * 512 + d];
  // Wt[p][n][k]: k=2d -> xr coeff, k=2d+1 -> xi coeff; n=2j -> yr, n=2j+1 -> yi.
  unsigned pack = (n & 1) ? pk2(im, r) : pk2(r, -im);
  wt[((size_t)p << 19) + ((size_t)n << 9) + d] = pack;
}

// ---------------------------------------------------------------- projections
__global__ __launch_bounds__(256) void proj_gemm(
    const float* __restrict__ xq, const float* __restrict__ xk,
    const float* __restrict__ xv,
    const unsigned short* __restrict__ wt,
    const unsigned short* __restrict__ aoin,
    unsigned short* __restrict__ qint, unsigned short* __restrict__ kcw,
    unsigned short* __restrict__ vtr, unsigned short* __restrict__ vti,
    float* __restrict__ outp, int mode) {
  __shared__ __align__(16) unsigned short As[128][40];  // [m][k], +8 pad
  __shared__ __align__(16) unsigned short Bs[128][40];  // [n][k] (Wt already transposed)
  const int z = (mode == 0) ? blockIdx.z : 3;
  const int tid = threadIdx.x;
  const int m0 = blockIdx.x * 128, n0 = blockIdx.y * 128;
  const int w = tid >> 6, lane = tid & 63;
  const int quad = lane >> 4, l16 = lane & 15;
  const int wm = (w >> 1) * 64, wn = (w & 1) * 64;
  const unsigned short* wtp = wt + ((size_t)z << 20);
  const float* xin = (z == 0) ? xq : ((z == 1) ? xk : xv);

  f32x4 acc[4][4];
  #pragma unroll
  for (int i = 0; i < 4; i++)
    #pragma unroll
    for (int j = 0; j < 4; j++) acc[i][j] = (f32x4){0.f, 0.f, 0.f, 0.f};

  const int rB = tid >> 2, cB = (tid & 3) * 8;
  const int rA = tid >> 1, cA = (tid & 1) * 16;

  for (int k0 = 0; k0 < 1024; k0 += 32) {
    __syncthreads();
    {  // stage B tile (bf16, rows = n)
      uint4 b0 = *(const uint4*)(wtp + (size_t)(n0 + rB) * 1024 + k0 + cB);
      uint4 b1 = *(const uint4*)(wtp + (size_t)(n0 + rB + 64) * 1024 + k0 + cB);
      *(uint4*)&Bs[rB][cB] = b0;
      *(uint4*)&Bs[rB + 64][cB] = b1;
    }
    if (mode == 0) {  // stage A: fp32 -> bf16
      const float4* src = (const float4*)(xin + (size_t)(m0 + rA) * 1024 + k0 + cA);
      float4 a0 = src[0], a1 = src[1], a2 = src[2], a3 = src[3];
      uint4 u0 = make_uint4(pk2(a0.x, a0.y), pk2(a0.z, a0.w),
                            pk2(a1.x, a1.y), pk2(a1.z, a1.w));
      uint4 u1 = make_uint4(pk2(a2.x, a2.y), pk2(a2.z, a2.w),
                            pk2(a3.x, a3.y), pk2(a3.z, a3.w));
      *(uint4*)&As[rA][cA] = u0;
      *(uint4*)&As[rA][cA + 8] = u1;
    } else {  // stage A: bf16 passthrough (attention output)
      const uint4* src = (const uint4*)(aoin + (size_t)(m0 + rA) * 1024 + k0 + cA);
      *(uint4*)&As[rA][cA] = src[0];
      *(uint4*)&As[rA][cA + 8] = src[1];
    }
    __syncthreads();
    bf16x8 af[4], bfr[4];
    #pragma unroll
    for (int mt = 0; mt < 4; mt++)
      af[mt] = *(const bf16x8*)&As[wm + mt * 16 + l16][quad * 8];
    #pragma unroll
    for (int nt = 0; nt < 4; nt++)
      bfr[nt] = *(const bf16x8*)&Bs[wn + nt * 16 + l16][quad * 8];
    #pragma unroll
    for (int mt = 0; mt < 4; mt++)
      #pragma unroll
      for (int nt = 0; nt < 4; nt++)
        acc[mt][nt] = __builtin_amdgcn_mfma_f32_16x16x32_bf16(
            af[mt], bfr[nt], acc[mt][nt], 0, 0, 0);
  }

  // epilogue: C layout col=lane&15, row=quad*4+reg (m89-verified)
  #pragma unroll
  for (int mt = 0; mt < 4; mt++) {
    #pragma unroll
    for (int nt = 0; nt < 4; nt++) {
      #pragma unroll
      for (int r = 0; r < 4; r++) {
        int m = m0 + wm + mt * 16 + quad * 4 + r;
        int n = n0 + wn + nt * 16 + l16;
        float v = acc[mt][nt][r];
        if (z == 3) {
          outp[(size_t)m * 1024 + n] = v;
        } else {
          int b = m >> 10, s = m & 1023;
          int h = n >> 7;
          if (z == 0) {
            // pre-scale by 1/sqrt(DH)=0.125 (exact in bf16)
            qint[(((size_t)(b * 8 + h) * 1024 + s) << 7) + (n & 127)] = f2bf(v * 0.125f);
          } else if (z == 1) {
            // conj-interleave: even col = kr, odd col = -ki
            kcw[(((size_t)(b * 8 + h) * 1024 + s) << 7) + (n & 127)] = f2bf((n & 1) ? -v : v);
          } else {
            int dh = (n >> 1) & 63;
            unsigned short* vp = (n & 1) ? vti : vtr;
            vp[(((size_t)(b * 8 + h) * 64 + dh) << 10) + s] = f2bf(v);
          }
        }
      }
    }
  }
}

// ---------------------------------------------------------------- attention
__global__ __launch_bounds__(256) void attn_kernel(
    const unsigned short* __restrict__ qint,
    const unsigned short* __restrict__ kcw,
    const unsigned short* __restrict__ vtr,
    const unsigned short* __restrict__ vti,
    unsigned* __restrict__ aout) {  // uint view: packed (o_r, o_i) bf16x2
  __shared__ __align__(16) float s_r[64][68];
  __shared__ __align__(16) float s_i[64][68];
  __shared__ float al_r[64], al_i[64], lr_s[64], li_s[64];
  const int tid = threadIdx.x;
  const int bh = blockIdx.x >> 4, qt = blockIdx.x & 15;
  const int q0 = qt * 64;
  const int w = tid >> 6, lane = tid & 63;
  const int quad = lane >> 4, l16 = lane & 15;
  const unsigned short* qb = qint + (size_t)bh * 1024 * 128;
  const unsigned short* kb = kcw + (size_t)bh * 1024 * 128;
  const unsigned short* vrb = vtr + (size_t)bh * 64 * 1024;
  const unsigned short* vib = vti + (size_t)bh * 64 * 1024;

  // Q A-fragments (A[m=lane&15][k=quad*8+j], m120-verified), resident all loop
  bf16x8 qf[4];
  #pragma unroll
  for (int kc = 0; kc < 4; kc++)
    qf[kc] = *(const bf16x8*)(qb + (size_t)(q0 + w * 16 + l16) * 128 + kc * 32 + quad * 8);

  f32x4 orr[4], ori[4], oir[4], oii[4];
  #pragma unroll
  for (int nt = 0; nt < 4; nt++) {
    orr[nt] = (f32x4){0.f, 0.f, 0.f, 0.f};
    ori[nt] = (f32x4){0.f, 0.f, 0.f, 0.f};
    oir[nt] = (f32x4){0.f, 0.f, 0.f, 0.f};
    oii[nt] = (f32x4){0.f, 0.f, 0.f, 0.f};
  }
  float mr = -1e30f, mi2 = -1e30f, lr = 0.f, li = 0.f;
  const int srow = tid >> 2, spart = tid & 3;  // 4 threads per score row

  for (int t = 0; t < 16; t++) {
    const int kp0 = t * 64;
    f32x4 sr[4], si[4];
    #pragma unroll
    for (int nt = 0; nt < 4; nt++) {
      sr[nt] = (f32x4){0.f, 0.f, 0.f, 0.f};
      si[nt] = (f32x4){0.f, 0.f, 0.f, 0.f};
    }
    // ---- complex QK^T for this 64-key tile
    #pragma unroll
    for (int nt = 0; nt < 4; nt++) {
      const unsigned short* krow = kb + (size_t)(kp0 + nt * 16 + l16) * 128;
      #pragma unroll
      for (int kc = 0; kc < 4; kc++) {
        union { bf16x8 v; unsigned u[4]; uint4 q; } kf, kd;
        kf.q = *(const uint4*)(krow + kc * 32 + quad * 8);
        #pragma unroll
        for (int e = 0; e < 4; e++) {  // (kr,-ki) -> (ki,kr): halfword swap + sign xor
          unsigned x = kf.u[e];
          kd.u[e] = ((x >> 16) | (x << 16)) ^ 0x8000u;
        }
        sr[nt] = __builtin_amdgcn_mfma_f32_16x16x32_bf16(qf[kc], kf.v, sr[nt], 0, 0, 0);
        si[nt] = __builtin_amdgcn_mfma_f32_16x16x32_bf16(qf[kc], kd.v, si[nt], 0, 0, 0);
      }
    }
    #pragma unroll
    for (int nt = 0; nt < 4; nt++)
      #pragma unroll
      for (int r = 0; r < 4; r++) {
        s_r[w * 16 + quad * 4 + r][nt * 16 + l16] = sr[nt][r];
        s_i[w * 16 + quad * 4 + r][nt * 16 + l16] = si[nt][r];
      }
    __syncthreads();
    // ---- online softmax, real part
    {
      float* row = &s_r[srow][spart * 16];
      float v0[16];
      float mx = -1e30f;
      #pragma unroll
      for (int i = 0; i < 16; i++) { v0[i] = row[i]; mx = fmaxf(mx, v0[i]); }
      mx = fmaxf(mx, __shfl_xor(mx, 1));
      mx = fmaxf(mx, __shfl_xor(mx, 2));
      float mn = fmaxf(mr, mx);
      float alpha = __expf(mr - mn);
      float sum = 0.f;
      #pragma unroll
      for (int i = 0; i < 16; i++) { float p = __expf(v0[i] - mn); row[i] = p; sum += p; }
      sum += __shfl_xor(sum, 1);
      sum += __shfl_xor(sum, 2);
      lr = lr * alpha + sum; mr = mn;
      if (spart == 0) al_r[srow] = alpha;
    }
    // ---- online softmax, imag part
    {
      float* row = &s_i[srow][spart * 16];
      float v0[16];
      float mx = -1e30f;
      #pragma unroll
      for (int i = 0; i < 16; i++) { v0[i] = row[i]; mx = fmaxf(mx, v0[i]); }
      mx = fmaxf(mx, __shfl_xor(mx, 1));
      mx = fmaxf(mx, __shfl_xor(mx, 2));
      float mn = fmaxf(mi2, mx);
      float alpha = __expf(mi2 - mn);
      float sum = 0.f;
      #pragma unroll
      for (int i = 0; i < 16; i++) { float p = __expf(v0[i] - mn); row[i] = p; sum += p; }
      sum += __shfl_xor(sum, 1);
      sum += __shfl_xor(sum, 2);
      li = li * alpha + sum; mi2 = mn;
      if (spart == 0) al_i[srow] = alpha;
    }
    __syncthreads();
    // ---- rescale accumulators (alpha_r for a_r terms, alpha_i for a_i terms)
    float ar[4], ai2[4];
    #pragma unroll
    for (int r = 0; r < 4; r++) {
      ar[r] = al_r[w * 16 + quad * 4 + r];
      ai2[r] = al_i[w * 16 + quad * 4 + r];
    }
    #pragma unroll
    for (int nt = 0; nt < 4; nt++)
      #pragma unroll
      for (int r = 0; r < 4; r++) {
        orr[nt][r] *= ar[r];  ori[nt][r] *= ar[r];
        oir[nt][r] *= ai2[r]; oii[nt][r] *= ai2[r];
      }
    // ---- P fragments (LDS C-layout -> A-layout, fp32 -> bf16)
    bf16x8 pr[2], pi3[2];
    #pragma unroll
    for (int kc = 0; kc < 2; kc++) {
      const float4* p0 = (const float4*)&s_r[w * 16 + l16][kc * 32 + quad * 8];
      float4 x0 = p0[0], x1 = p0[1];
      union { bf16x8 v; uint4 q; } pu;
      pu.q = make_uint4(pk2(x0.x, x0.y), pk2(x0.z, x0.w), pk2(x1.x, x1.y), pk2(x1.z, x1.w));
      pr[kc] = pu.v;
      const float4* p1 = (const float4*)&s_i[w * 16 + l16][kc * 32 + quad * 8];
      float4 y0 = p1[0], y1 = p1[1];
      pu.q = make_uint4(pk2(y0.x, y0.y), pk2(y0.z, y0.w), pk2(y1.x, y1.y), pk2(y1.z, y1.w));
      pi3[kc] = pu.v;
    }
    // ---- P @ V (4 combos)
    #pragma unroll
    for (int nt = 0; nt < 4; nt++) {
      #pragma unroll
      for (int kc = 0; kc < 2; kc++) {
        size_t vo = (size_t)(nt * 16 + l16) * 1024 + kp0 + kc * 32 + quad * 8;
        bf16x8 vfr = *(const bf16x8*)(vrb + vo);
        bf16x8 vfi = *(const bf16x8*)(vib + vo);
        orr[nt] = __builtin_amdgcn_mfma_f32_16x16x32_bf16(pr[kc],  vfr, orr[nt], 0, 0, 0);
        ori[nt] = __builtin_amdgcn_mfma_f32_16x16x32_bf16(pr[kc],  vfi, ori[nt], 0, 0, 0);
        oir[nt] = __builtin_amdgcn_mfma_f32_16x16x32_bf16(pi3[kc], vfr, oir[nt], 0, 0, 0);
        oii[nt] = __builtin_amdgcn_mfma_f32_16x16x32_bf16(pi3[kc], vfi, oii[nt], 0, 0, 0);
      }
    }
    __syncthreads();  // protect s_lds before next iteration overwrites
  }
  if (spart == 0) { lr_s[srow] = lr; li_s[srow] = li; }
  __syncthreads();
  float rl[4], il[4];
  #pragma unroll
  for (int r = 0; r < 4; r++) {
    rl[r] = 1.f / lr_s[w * 16 + quad * 4 + r];
    il[r] = 1.f / li_s[w * 16 + quad * 4 + r];
  }
  const int b = bh >> 3, h = bh & 7;
  #pragma unroll
  for (int nt = 0; nt < 4; nt++) {
    #pragma unroll
    for (int r = 0; r < 4; r++) {
      float o_r = orr[nt][r] * rl[r] - oii[nt][r] * il[r];
      float o_i = ori[nt][r] * rl[r] + oir[nt][r] * il[r];
      int sr2 = q0 + w * 16 + quad * 4 + r;
      int dh = nt * 16 + l16;
      aout[(size_t)(b * 1024 + sr2) * 512 + (h * 64 + dh)] = pk2(o_r, o_i);
    }
  }
}

// ---------------------------------------------------------------- launcher
extern "C" void kernel_launch(void* const* d_in, const int* in_sizes, int n_in,
                              void* d_out, int out_size, void* d_ws, size_t ws_size,
                              hipStream_t stream) {
  const float* xq = (const float*)d_in[0];
  const float* xk = (const float*)d_in[1];
  const float* xv = (const float*)d_in[2];
  const float* wq_r = (const float*)d_in[3];
  const float* wq_i = (const float*)d_in[4];
  const float* wk_r = (const float*)d_in[5];
  const float* wk_i = (const float*)d_in[6];
  const float* wv_r = (const float*)d_in[7];
  const float* wv_i = (const float*)d_in[8];
  const float* wo_r = (const float*)d_in[9];
  const float* wo_i = (const float*)d_in[10];
  float* outp = (float*)d_out;

  char* ws = (char*)d_ws;
  unsigned short* wt   = (unsigned short*)(ws);                        //  8 MiB: Wt[4][1024][1024] bf16
  unsigned short* qint = (unsigned short*)(ws + ((size_t)8  << 20));   // 16 MiB: [B][H][S][128]
  unsigned short* kcw  = (unsigned short*)(ws + ((size_t)24 << 20));   // 16 MiB: [B][H][S][128]
  unsigned short* vtr  = (unsigned short*)(ws + ((size_t)40 << 20));   //  8 MiB: [B][H][64][S]
  unsigned short* vti  = (unsigned short*)(ws + ((size_t)48 << 20));   //  8 MiB
  unsigned short* ao   = (unsigned short*)(ws + ((size_t)56 << 20));   // 16 MiB: [B*S][1024]
  // total 72 MiB of d_ws

  prep_weights<<<8192, 256, 0, stream>>>(wq_r, wq_i, wk_r, wk_i, wv_r, wv_i,
                                         wo_r, wo_i, (unsigned*)wt);
  dim3 g1(64, 8, 3);
  proj_gemm<<<g1, 256, 0, stream>>>(xq, xk, xv, wt, ao, qint, kcw, vtr, vti,
                                    outp, 0);
  attn_kernel<<<1024, 256, 0, stream>>>(qint, kcw, vtr, vti, (unsigned*)ao);
  dim3 g2(64, 8, 1);
  proj_gemm<<<g2, 256, 0, stream>>>(xq, xk, xv, wt, ao, qint, kcw, vtr, vti,
                                    outp, 3);
}